// Round 7
// baseline (223.947 us; speedup 1.0000x reference)
//
#include <hip/hip_runtime.h>
#include <math.h>

// Problem constants (from reference)
#define B_DIM 16
#define T_DIM 2048
#define D_DIM 4096
#define G_DIM 8
#define GS    512
#define H_DIM 16
#define CHUNKS 128          // t-chunks per b (16 rows each)
#define NPARTIAL (B_DIM * G_DIM * CHUNKS)   // 16384 doubles

// Output layout (float32, concatenated flat in return order)
#define OUT_DBITS   0        // [16,8]   = 128
#define OUT_GIDX    128      // [16,4096]= 65536  (float4 base = 32)
#define OUT_EMB     65664    // [16,8,512] = 65536 (float4 base = 16416)
#define OUT_BLOSS   131200   // scalar
#define OUT_DIV     131201   // scalar
#define OUT_BPROBS  131202   // [16,8] = 128

// Workspace layout (bytes)
#define WS_PARTIALS 0        // 16384 * 8 B
#define WS_ENT      131072   // 16 f32
#define WS_BS       131136   // 16 f32
#define WS_BCTR     131200   // 16 u32  -- zeroed by memset each call
#define WS_GCTR     131264   // 1 u32   -- zeroed by memset each call
#define WS_CTR_BYTES 68

typedef float f32x4 __attribute__((ext_vector_type(4)));

// ---------------------------------------------------------------------------
// Tiny MLP (pure function of inputs -> deterministic wherever recomputed).
// All outputs through pointers so the caller can use LDS, keeping register
// pressure off the streaming path.
// ---------------------------------------------------------------------------
__device__ __forceinline__ void run_mlp(const float* gi8, int b,
                                        const float* __restrict__ u,
                                        const float* __restrict__ W1,
                                        const float* __restrict__ b1,
                                        const float* __restrict__ ln_g,
                                        const float* __restrict__ ln_b,
                                        const float* __restrict__ W2,
                                        const float* __restrict__ b2,
                                        float* p,        // [8]
                                        float* hard,     // [8]
                                        float (*bw)[3],  // [8][3]
                                        float* entb_out, float* bs_out) {
    float h[H_DIM];
    #pragma unroll
    for (int i = 0; i < H_DIM; ++i) {
        float a = b1[i];
        #pragma unroll
        for (int g = 0; g < G_DIM; ++g) a += gi8[g] * W1[g * H_DIM + i];
        h[i] = 0.5f * a * (1.0f + erff(a * 0.70710678118654752440f));
    }
    float mu = 0.f;
    #pragma unroll
    for (int i = 0; i < H_DIM; ++i) mu += h[i];
    mu *= (1.0f / (float)H_DIM);
    float var = 0.f;
    #pragma unroll
    for (int i = 0; i < H_DIM; ++i) { float d = h[i] - mu; var += d * d; }
    var *= (1.0f / (float)H_DIM);
    const float inv = rsqrtf(var + 1e-5f);
    #pragma unroll
    for (int i = 0; i < H_DIM; ++i) h[i] = (h[i] - mu) * inv * ln_g[i] + ln_b[i];

    float z[G_DIM];
    #pragma unroll
    for (int j = 0; j < G_DIM; ++j) {
        float a = b2[j];
        #pragma unroll
        for (int i = 0; i < H_DIM; ++i) a += h[i] * W2[i * G_DIM + j];
        const float uu = u[b * G_DIM + j];
        z[j] = a + (-logf(-logf(uu + 1e-8f) + 1e-8f));
    }
    float m = z[0];
    #pragma unroll
    for (int j = 1; j < G_DIM; ++j) m = fmaxf(m, z[j]);
    float ssum = 0.f;
    #pragma unroll
    for (int j = 0; j < G_DIM; ++j) { p[j] = expf(z[j] - m); ssum += p[j]; }
    const float rs = 1.0f / ssum;

    float asum = 0.f;
    #pragma unroll
    for (int j = 0; j < G_DIM; ++j) {
        p[j] *= rs;
        z[j] = 2.0f + p[j] * 6.0f;       // reuse z as alloc
        asum += z[j];
    }
    const float scale = 32.0f / asum;    // budget = 4 * 8

    float entb = 0.f, bs = 0.f;
    #pragma unroll
    for (int j = 0; j < G_DIM; ++j) {
        float a = z[j] * scale;
        a = fminf(fmaxf(a, 2.0f), 8.0f);
        // nearest of {2,4,8}; argmin tie-break -> lower index
        const float hd = (a <= 3.0f) ? 2.0f : ((a <= 6.0f) ? 4.0f : 8.0f);
        hard[j] = hd;
        entb += p[j] * logf(p[j] + 1e-8f);
        bs += hd;
        const float x0 = expf(-fabsf(hd - 2.0f));
        const float x1 = expf(-fabsf(hd - 4.0f));
        const float x2 = expf(-fabsf(hd - 8.0f));
        const float mm = fmaxf(x0, fmaxf(x1, x2));
        const float e0 = expf(x0 - mm), e1 = expf(x1 - mm), e2 = expf(x2 - mm);
        const float ir = 1.0f / (e0 + e1 + e2);
        bw[j][0] = e0 * ir;
        bw[j][1] = e1 * ir;
        bw[j][2] = e2 * ir;
    }
    *entb_out = entb;
    *bs_out = bs;
}

// ---------------------------------------------------------------------------
// Single fused kernel. 2048 blocks x 256 threads.
//  phase A (blocks 0..63): write constant group_indices (no dependencies).
//  phase B (all blocks): stream-reduce a contiguous 256 KB slab -> 8 group
//    partials (NT loads, f64 accumulation, wave shuffles).
//  phase C: per-b ticket counter; the block that completes b's 128th chunk
//    becomes b's finisher: reduces b's 1024 partials, runs the MLP (LDS
//    outputs), writes dbits/bprobs/embeddings for b. A 16-ticket global
//    counter elects the scalar writer. No spinning anywhere -> no
//    co-residency assumption. Counters zeroed by a memset node each call.
// ---------------------------------------------------------------------------
__global__ __launch_bounds__(256) void k_main(const float* __restrict__ scores,
                                              const float* __restrict__ u,
                                              const float* __restrict__ W1,
                                              const float* __restrict__ b1,
                                              const float* __restrict__ ln_g,
                                              const float* __restrict__ ln_b,
                                              const float* __restrict__ W2,
                                              const float* __restrict__ b2,
                                              const float* __restrict__ emb,
                                              float* __restrict__ out,
                                              void* __restrict__ ws) {
    double* partials = (double*)((char*)ws + WS_PARTIALS);
    float*  ws_ent   = (float*)((char*)ws + WS_ENT);
    float*  ws_bs    = (float*)((char*)ws + WS_BS);
    unsigned* bctr   = (unsigned*)((char*)ws + WS_BCTR);
    unsigned* gctr   = (unsigned*)((char*)ws + WS_GCTR);

    const int bid   = blockIdx.x;        // [0, 2048)
    const int b     = bid >> 7;
    const int chunk = bid & 127;
    const int tid   = threadIdx.x;

    float4* o4 = reinterpret_cast<float4*>(out);

    // --- phase A: constant group_indices (blocks 0..63) ---
    if (bid < 64) {
        const int l   = bid * 256 + tid;      // [0,16384) float4 of gidx
        const int g   = (l >> 7) & 7;
        const float gv = (float)g;            // d // 512
        o4[(OUT_GIDX / 4) + l] = make_float4(gv, gv, gv, gv);
    }

    // --- phase B: stream reduce ---
    const f32x4* base = reinterpret_cast<const f32x4*>(
        scores + (size_t)b * T_DIM * D_DIM + (size_t)chunk * 16 * D_DIM);

    double a0 = 0.0, a1 = 0.0, a2 = 0.0, a3 = 0.0;
    #pragma unroll 4
    for (int r = 0; r < 16; ++r) {
        const f32x4* row = base + (size_t)r * (D_DIM / 4);
        const f32x4 v0 = __builtin_nontemporal_load(row + tid);
        const f32x4 v1 = __builtin_nontemporal_load(row + tid + 256);
        const f32x4 v2 = __builtin_nontemporal_load(row + tid + 512);
        const f32x4 v3 = __builtin_nontemporal_load(row + tid + 768);
        a0 += (double)v0.x + (double)v0.y + (double)v0.z + (double)v0.w;
        a1 += (double)v1.x + (double)v1.y + (double)v1.z + (double)v1.w;
        a2 += (double)v2.x + (double)v2.y + (double)v2.z + (double)v2.w;
        a3 += (double)v3.x + (double)v3.y + (double)v3.z + (double)v3.w;
    }

    // Per-wave reduce: within a wave, group of phase p is g = 2p + (wave>>1).
    const int lane = tid & 63;
    const int wave = tid >> 6;
    __shared__ double wsum[4][4];        // [wave][phase]
    __shared__ int s_fin, s_fin2;
    if (tid == 0) { s_fin = 0; s_fin2 = 0; }
    double acc[4] = {a0, a1, a2, a3};
    #pragma unroll
    for (int p = 0; p < 4; ++p) {
        double v = acc[p];
        #pragma unroll
        for (int off = 32; off > 0; off >>= 1) v += __shfl_down(v, off, 64);
        if (lane == 0) wsum[wave][p] = v;
    }
    __syncthreads();

    // --- phase C: partials write + per-b ticket ---
    if (tid < G_DIM) {
        // group g=tid: phase p = g>>1, waves w0 = 2*(g&1), w0+1
        const int p  = tid >> 1;
        const int w0 = (tid & 1) * 2;
        partials[(size_t)(b * G_DIM + tid) * CHUNKS + chunk] = wsum[w0][p] + wsum[w0 + 1][p];
        __threadfence();
        if (atomicAdd(&bctr[b], 1u) == (unsigned)(CHUNKS * G_DIM - 1)) s_fin = 1;
    }
    __syncthreads();
    if (!s_fin) return;

    // ===== b-finisher block: all of b's partials are globally visible =====
    __threadfence();   // acquire side

    __shared__ float s_gi[G_DIM];
    __shared__ float s_p[G_DIM], s_hard[G_DIM], s_w[G_DIM][3];
    __shared__ float s_entb, s_bsb;

    // group means: 1024 doubles, 4 per thread, width-32 shuffle reduce
    const double* pb = partials + (size_t)b * G_DIM * CHUNKS;
    double v = 0.0;
    #pragma unroll
    for (int k = 0; k < 4; ++k) v += pb[tid * 4 + k];
    #pragma unroll
    for (int off = 16; off > 0; off >>= 1) v += __shfl_down(v, off, 32);
    if ((tid & 31) == 0)
        s_gi[tid >> 5] = (float)(v * (1.0 / ((double)T_DIM * (double)GS)));
    __syncthreads();

    if (tid == 0)
        run_mlp(s_gi, b, u, W1, b1, ln_g, ln_b, W2, b2,
                s_p, s_hard, s_w, &s_entb, &s_bsb);
    __syncthreads();

    if (tid < G_DIM) {
        out[OUT_DBITS  + b * G_DIM + tid] = s_hard[tid];
        out[OUT_BPROBS + b * G_DIM + tid] = s_p[tid];
    }
    if (tid == 0) {
        ws_ent[b] = s_entb;
        ws_bs[b]  = s_bsb;
        __threadfence();
        if (atomicAdd(gctr, 1u) == (unsigned)(B_DIM - 1)) s_fin2 = 1;
    }

    // embeddings for this b: 1024 float4, 4 per thread
    const float4* e4 = reinterpret_cast<const float4*>(emb);  // [3][128]
    #pragma unroll
    for (int i = 0; i < 4; ++i) {
        const int k  = tid + 256 * i;     // [0,1024)
        const int g  = k >> 7;
        const int j4 = k & 127;
        const float4 e0 = e4[0 * 128 + j4];
        const float4 e1 = e4[1 * 128 + j4];
        const float4 e2 = e4[2 * 128 + j4];
        const float w0 = s_w[g][0], w1 = s_w[g][1], w2 = s_w[g][2];
        float4 r;
        r.x = w0 * e0.x + w1 * e1.x + w2 * e2.x;
        r.y = w0 * e0.y + w1 * e1.y + w2 * e2.y;
        r.z = w0 * e0.z + w1 * e1.z + w2 * e2.z;
        r.w = w0 * e0.w + w1 * e1.w + w2 * e2.w;
        o4[(OUT_EMB / 4) + b * 1024 + k] = r;
    }

    __syncthreads();
    if (s_fin2 && tid == 0) {
        // last finisher: all 16 ent/bs entries are globally visible
        __threadfence();
        float tb = 0.f, te = 0.f;
        #pragma unroll
        for (int bb = 0; bb < B_DIM; ++bb) { tb += ws_bs[bb]; te += ws_ent[bb]; }
        const float mb = tb * (1.0f / (float)(B_DIM * G_DIM));
        out[OUT_BLOSS] = (mb - 4.0f) * (mb - 4.0f);
        out[OUT_DIV]   = -te * (1.0f / (float)B_DIM);
    }
}

// ---------------------------------------------------------------------------
extern "C" void kernel_launch(void* const* d_in, const int* in_sizes, int n_in,
                              void* d_out, int out_size, void* d_ws, size_t ws_size,
                              hipStream_t stream) {
    const float* scores = (const float*)d_in[0];
    const float* u      = (const float*)d_in[1];
    const float* W1     = (const float*)d_in[2];
    const float* b1     = (const float*)d_in[3];
    const float* ln_g   = (const float*)d_in[4];
    const float* ln_b   = (const float*)d_in[5];
    const float* W2     = (const float*)d_in[6];
    const float* b2     = (const float*)d_in[7];
    const float* emb    = (const float*)d_in[8];
    float* out = (float*)d_out;

    // zero the ticket counters every call (ws is poisoned 0xAA, never re-poisoned)
    hipMemsetAsync((char*)d_ws + WS_BCTR, 0, WS_CTR_BYTES, stream);

    k_main<<<B_DIM * CHUNKS, 256, 0, stream>>>(scores, u, W1, b1, ln_g, ln_b,
                                               W2, b2, emb, out, d_ws);
}

// Round 8
// 94.916 us; speedup vs baseline: 2.3594x; 2.3594x over previous
//
#include <hip/hip_runtime.h>
#include <math.h>

// Problem constants (from reference)
#define B_DIM 16
#define T_DIM 2048
#define D_DIM 4096
#define G_DIM 8
#define GS    512
#define H_DIM 16
#define CHUNKS 128          // t-chunks per b (16 rows each)
#define NPARTIAL (B_DIM * G_DIM * CHUNKS)   // 16384 doubles

// Output layout (float32, concatenated flat in return order)
#define OUT_DBITS   0        // [16,8]   = 128
#define OUT_GIDX    128      // [16,4096]= 65536  (float4 base = 32)
#define OUT_EMB     65664    // [16,8,512] = 65536 (float4 base = 16416)
#define OUT_BLOSS   131200   // scalar
#define OUT_DIV     131201   // scalar
#define OUT_BPROBS  131202   // [16,8] = 128

typedef float f32x4 __attribute__((ext_vector_type(4)));

// ---------------------------------------------------------------------------
// Kernel 1: stream-reduce importance_scores [B,T,D] -> per-(b,g,chunk)
// partials. Contiguous 256 KB slab per block, NT loads (zero-reuse stream),
// f64 accumulation, wave-shuffle reduce. Blocks 0..63 additionally emit the
// constant group_indices plane (NT stores; no data dependencies, ~3 VGPRs).
// NOTE: keep ALL scalar/MLP code out of this kernel — R7 showed the finisher
// path's register pressure halves occupancy and drops stream BW 6.05->2.4 TB/s.
// ---------------------------------------------------------------------------
__global__ __launch_bounds__(256) void k_reduce(const float* __restrict__ scores,
                                                double* __restrict__ partials,
                                                float* __restrict__ out) {
    const int bid   = blockIdx.x;        // [0, 2048)
    const int b     = bid >> 7;
    const int chunk = bid & 127;
    const int tid   = threadIdx.x;

    // constant group_indices: blocks 0..63, one float4 per thread
    if (bid < 64) {
        const int l = bid * 256 + tid;        // [0,16384) float4 index
        const float gv = (float)((l >> 7) & 7);   // d // 512
        f32x4 t = {gv, gv, gv, gv};
        __builtin_nontemporal_store(t, reinterpret_cast<f32x4*>(out) + (OUT_GIDX / 4) + l);
    }

    const f32x4* base = reinterpret_cast<const f32x4*>(
        scores + (size_t)b * T_DIM * D_DIM + (size_t)chunk * 16 * D_DIM);

    double a0 = 0.0, a1 = 0.0, a2 = 0.0, a3 = 0.0;
    #pragma unroll 4
    for (int r = 0; r < 16; ++r) {
        const f32x4* row = base + (size_t)r * (D_DIM / 4);
        const f32x4 v0 = __builtin_nontemporal_load(row + tid);
        const f32x4 v1 = __builtin_nontemporal_load(row + tid + 256);
        const f32x4 v2 = __builtin_nontemporal_load(row + tid + 512);
        const f32x4 v3 = __builtin_nontemporal_load(row + tid + 768);
        a0 += (double)v0.x + (double)v0.y + (double)v0.z + (double)v0.w;
        a1 += (double)v1.x + (double)v1.y + (double)v1.z + (double)v1.w;
        a2 += (double)v2.x + (double)v2.y + (double)v2.z + (double)v2.w;
        a3 += (double)v3.x + (double)v3.y + (double)v3.z + (double)v3.w;
    }

    // Per-wave reduce: within a wave, group of phase p is g = 2p + (wave>>1).
    const int lane = tid & 63;
    const int wave = tid >> 6;
    __shared__ double wsum[4][4];        // [wave][phase]
    double acc[4] = {a0, a1, a2, a3};
    #pragma unroll
    for (int p = 0; p < 4; ++p) {
        double v = acc[p];
        #pragma unroll
        for (int off = 32; off > 0; off >>= 1) v += __shfl_down(v, off, 64);
        if (lane == 0) wsum[wave][p] = v;
    }
    __syncthreads();

    if (tid < G_DIM) {
        // group g: phase p = g>>1, waves w0 = 2*(g&1), w0+1
        const int p  = tid >> 1;
        const int w0 = (tid & 1) * 2;
        partials[(size_t)(b * G_DIM + tid) * CHUNKS + chunk] = wsum[w0][p] + wsum[w0 + 1][p];
    }
}

// ---------------------------------------------------------------------------
// Shared MLP routine (pure function of inputs -> deterministic wherever
// recomputed): Linear -> GELU(exact) -> LayerNorm -> Linear -> (+gumbel)
// -> softmax -> alloc -> budget rescale -> clip -> discretize -> bit_w.
// ---------------------------------------------------------------------------
__device__ __forceinline__ void run_mlp(const float* __restrict__ gi8, int b,
                                        const float* __restrict__ u,
                                        const float* __restrict__ W1,
                                        const float* __restrict__ b1,
                                        const float* __restrict__ ln_g,
                                        const float* __restrict__ ln_b,
                                        const float* __restrict__ W2,
                                        const float* __restrict__ b2,
                                        float* __restrict__ p,      // [8]
                                        float* __restrict__ hard,   // [8]
                                        float (*bw)[3],             // [8][3]
                                        float* entb_out, float* bs_out) {
    float h[H_DIM];
    #pragma unroll
    for (int i = 0; i < H_DIM; ++i) {
        float a = b1[i];
        #pragma unroll
        for (int g = 0; g < G_DIM; ++g) a += gi8[g] * W1[g * H_DIM + i];
        h[i] = 0.5f * a * (1.0f + erff(a * 0.70710678118654752440f));
    }
    float mu = 0.f;
    #pragma unroll
    for (int i = 0; i < H_DIM; ++i) mu += h[i];
    mu *= (1.0f / (float)H_DIM);
    float var = 0.f;
    #pragma unroll
    for (int i = 0; i < H_DIM; ++i) { float d = h[i] - mu; var += d * d; }
    var *= (1.0f / (float)H_DIM);
    const float inv = rsqrtf(var + 1e-5f);
    #pragma unroll
    for (int i = 0; i < H_DIM; ++i) h[i] = (h[i] - mu) * inv * ln_g[i] + ln_b[i];

    float z[G_DIM];
    #pragma unroll
    for (int j = 0; j < G_DIM; ++j) {
        float a = b2[j];
        #pragma unroll
        for (int i = 0; i < H_DIM; ++i) a += h[i] * W2[i * G_DIM + j];
        const float uu = u[b * G_DIM + j];
        z[j] = a + (-logf(-logf(uu + 1e-8f) + 1e-8f));
    }
    float m = z[0];
    #pragma unroll
    for (int j = 1; j < G_DIM; ++j) m = fmaxf(m, z[j]);
    float ssum = 0.f;
    #pragma unroll
    for (int j = 0; j < G_DIM; ++j) { p[j] = expf(z[j] - m); ssum += p[j]; }
    const float rs = 1.0f / ssum;

    float asum = 0.f;
    #pragma unroll
    for (int j = 0; j < G_DIM; ++j) {
        p[j] *= rs;
        z[j] = 2.0f + p[j] * 6.0f;       // reuse z as alloc
        asum += z[j];
    }
    const float scale = 32.0f / asum;    // budget = 4 * 8

    float entb = 0.f, bs = 0.f;
    #pragma unroll
    for (int j = 0; j < G_DIM; ++j) {
        float a = z[j] * scale;
        a = fminf(fmaxf(a, 2.0f), 8.0f);
        // nearest of {2,4,8}; argmin tie-break -> lower index
        const float hd = (a <= 3.0f) ? 2.0f : ((a <= 6.0f) ? 4.0f : 8.0f);
        hard[j] = hd;
        entb += p[j] * logf(p[j] + 1e-8f);
        bs += hd;
        const float x0 = expf(-fabsf(hd - 2.0f));
        const float x1 = expf(-fabsf(hd - 4.0f));
        const float x2 = expf(-fabsf(hd - 8.0f));
        const float mm = fmaxf(x0, fmaxf(x1, x2));
        const float e0 = expf(x0 - mm), e1 = expf(x1 - mm), e2 = expf(x2 - mm);
        const float ir = 1.0f / (e0 + e1 + e2);
        bw[j][0] = e0 * ir;
        bw[j][1] = e1 * ir;
        bw[j][2] = e2 * ir;
    }
    *entb_out = entb;
    *bs_out = bs;
}

// ---------------------------------------------------------------------------
// Kernel 2 (tail): 64 blocks x 256 threads.
// Every block: reduce its own b's 1024 partials -> 8 group means (shuffle),
// thread 0 runs the MLP redundantly -> bit_w in LDS, then all 256 threads
// write one float4 of embeddings. Block 0 additionally performs the full
// per-b MLP pass and writes discrete_bits, bit_probs, and the two scalars.
// (group_indices now written by k_reduce.)
// ---------------------------------------------------------------------------
__global__ __launch_bounds__(256) void k_tail(const double* __restrict__ partials,
                                              const float* __restrict__ u,
                                              const float* __restrict__ W1,
                                              const float* __restrict__ b1,
                                              const float* __restrict__ ln_g,
                                              const float* __restrict__ ln_b,
                                              const float* __restrict__ W2,
                                              const float* __restrict__ b2,
                                              const float* __restrict__ emb,
                                              float* __restrict__ out) {
    const int blk = blockIdx.x;          // [0,64)
    const int b   = blk >> 2;
    const int q   = blk & 3;
    const int tid = threadIdx.x;

    __shared__ float s_gi[B_DIM * G_DIM];  // block0: all (b,g); others: [0..8)
    __shared__ float s_w[G_DIM][3];        // bit_w for this block's b
    __shared__ float s_ent[B_DIM], s_bs[B_DIM];

    if (blk == 0) {
        // --- full replica: all-b group means ---
        if (tid < 128) {
            double s = 0.0;
            #pragma unroll 8
            for (int c = 0; c < CHUNKS; ++c) s += partials[(size_t)tid * CHUNKS + c];
            s_gi[tid] = (float)(s * (1.0 / ((double)T_DIM * (double)GS)));
        }
        __syncthreads();
        if (tid < B_DIM) {
            float p[G_DIM], hard[G_DIM], bw[G_DIM][3], entb, bs;
            run_mlp(&s_gi[tid * G_DIM], tid, u, W1, b1, ln_g, ln_b, W2, b2,
                    p, hard, bw, &entb, &bs);
            #pragma unroll
            for (int j = 0; j < G_DIM; ++j) {
                out[OUT_DBITS  + tid * G_DIM + j] = hard[j];
                out[OUT_BPROBS + tid * G_DIM + j] = p[j];
            }
            s_ent[tid] = entb;
            s_bs[tid]  = bs;
            if (tid == 0) {           // this block's b == 0
                #pragma unroll
                for (int j = 0; j < G_DIM; ++j) {
                    s_w[j][0] = bw[j][0]; s_w[j][1] = bw[j][1]; s_w[j][2] = bw[j][2];
                }
            }
        }
        __syncthreads();
        if (tid == 0) {
            float tb = 0.f, te = 0.f;
            #pragma unroll
            for (int bb = 0; bb < B_DIM; ++bb) { tb += s_bs[bb]; te += s_ent[bb]; }
            const float mb = tb * (1.0f / (float)(B_DIM * G_DIM));
            out[OUT_BLOSS] = (mb - 4.0f) * (mb - 4.0f);
            out[OUT_DIV]   = -te * (1.0f / (float)B_DIM);
        }
    } else {
        // --- own-b group means: 1024 doubles, 4 per thread, shuffle reduce ---
        const double* pb = partials + (size_t)b * G_DIM * CHUNKS;
        double v = 0.0;
        #pragma unroll
        for (int k = 0; k < 4; ++k) v += pb[tid * 4 + k];
        // threads [g*32, g*32+32) hold group g = tid>>5; width-32 reduce
        #pragma unroll
        for (int off = 16; off > 0; off >>= 1) v += __shfl_down(v, off, 32);
        if ((tid & 31) == 0)
            s_gi[tid >> 5] = (float)(v * (1.0 / ((double)T_DIM * (double)GS)));
        __syncthreads();
        if (tid == 0) {
            float p[G_DIM], hard[G_DIM], bw[G_DIM][3], entb, bs;
            run_mlp(&s_gi[0], b, u, W1, b1, ln_g, ln_b, W2, b2,
                    p, hard, bw, &entb, &bs);
            #pragma unroll
            for (int j = 0; j < G_DIM; ++j) {
                s_w[j][0] = bw[j][0]; s_w[j][1] = bw[j][1]; s_w[j][2] = bw[j][2];
            }
        }
    }
    __syncthreads();

    // --- embedding write: one float4 per thread ---
    const int l  = blk * 256 + tid;       // [0,16384) float4 index
    const int g  = q * 2 + (tid >> 7);    // group within b
    const int j4 = tid & 127;

    const float4* e4 = reinterpret_cast<const float4*>(emb);  // [3][128]
    const float4 e0 = e4[0 * 128 + j4];
    const float4 e1 = e4[1 * 128 + j4];
    const float4 e2 = e4[2 * 128 + j4];
    const float w0 = s_w[g][0], w1 = s_w[g][1], w2 = s_w[g][2];

    float4 r;
    r.x = w0 * e0.x + w1 * e1.x + w2 * e2.x;
    r.y = w0 * e0.y + w1 * e1.y + w2 * e2.y;
    r.z = w0 * e0.z + w1 * e1.z + w2 * e2.z;
    r.w = w0 * e0.w + w1 * e1.w + w2 * e2.w;

    float4* o4 = reinterpret_cast<float4*>(out);
    o4[(OUT_EMB / 4) + l] = r;
}

// ---------------------------------------------------------------------------
extern "C" void kernel_launch(void* const* d_in, const int* in_sizes, int n_in,
                              void* d_out, int out_size, void* d_ws, size_t ws_size,
                              hipStream_t stream) {
    const float* scores = (const float*)d_in[0];
    const float* u      = (const float*)d_in[1];
    const float* W1     = (const float*)d_in[2];
    const float* b1     = (const float*)d_in[3];
    const float* ln_g   = (const float*)d_in[4];
    const float* ln_b   = (const float*)d_in[5];
    const float* W2     = (const float*)d_in[6];
    const float* b2     = (const float*)d_in[7];
    const float* emb    = (const float*)d_in[8];
    float* out = (float*)d_out;

    double* partials = (double*)d_ws;     // 16384 * 8 B

    k_reduce<<<B_DIM * CHUNKS, 256, 0, stream>>>(scores, partials, out);
    k_tail<<<64, 256, 0, stream>>>(partials, u, W1, b1, ln_g, ln_b, W2, b2, emb, out);
}